// Round 1
// baseline (773.660 us; speedup 1.0000x reference)
//
#include <hip/hip_runtime.h>

namespace {
constexpr int Bc  = 2;
constexpr int Sc  = 2048;
constexpr int Dc  = 768;
constexpr int Hc  = 12;
constexpr int DKc = 64;
constexpr int Mc  = Bc * Sc;   // 4096

// ---------------------------------------------------------------------------
// Y = X @ W^T (+bias). X:[M,Dc] row-major, W:[Dc,Dc] row-major [out,in].
// 64x64 output tile per block, BK=16, 256 threads, 4x4 registers per thread.
// SPLIT_HEADS: write Y in [B,H,S,DK] layout (for attention); else [M,Dc].
// ---------------------------------------------------------------------------
template <bool SPLIT_HEADS, bool ADD_BIAS>
__global__ __launch_bounds__(256, 4) void proj_kernel(
    const float* __restrict__ X, const float* __restrict__ W,
    const float* __restrict__ bias, float* __restrict__ Y)
{
  const int tx  = threadIdx.x;        // 0..15 -> output cols
  const int ty  = threadIdx.y;        // 0..15 -> output rows
  const int tid = ty * 16 + tx;
  const int m0  = blockIdx.x * 64;
  const int n0  = blockIdx.y * 64;

  __shared__ float As[16][68];        // [k][m], pad 4 keeps float4 16B-aligned
  __shared__ float Bs[16][68];        // [k][n]

  float acc[4][4] = {};

  const int lr = tid >> 2;            // 0..63 : tile row loaded by this thread
  const int lc = (tid & 3) * 4;       // 0/4/8/12 : k offset

  const float* xp = X + (size_t)(m0 + lr) * Dc + lc;
  const float* wp = W + (size_t)(n0 + lr) * Dc + lc;

  for (int k0 = 0; k0 < Dc; k0 += 16) {
    const float4 av = *reinterpret_cast<const float4*>(xp + k0);
    const float4 bv = *reinterpret_cast<const float4*>(wp + k0);
    __syncthreads();                  // previous tile's compute done
    As[lc + 0][lr] = av.x; As[lc + 1][lr] = av.y;
    As[lc + 2][lr] = av.z; As[lc + 3][lr] = av.w;
    Bs[lc + 0][lr] = bv.x; Bs[lc + 1][lr] = bv.y;
    Bs[lc + 2][lr] = bv.z; Bs[lc + 3][lr] = bv.w;
    __syncthreads();
#pragma unroll
    for (int kk = 0; kk < 16; ++kk) {
      const float4 a = *reinterpret_cast<const float4*>(&As[kk][ty * 4]);
      const float4 b = *reinterpret_cast<const float4*>(&Bs[kk][tx * 4]);
      const float aa[4] = {a.x, a.y, a.z, a.w};
      const float bb[4] = {b.x, b.y, b.z, b.w};
#pragma unroll
      for (int i = 0; i < 4; ++i)
#pragma unroll
        for (int j = 0; j < 4; ++j)
          acc[i][j] = fmaf(aa[i], bb[j], acc[i][j]);
    }
  }

  float4 badd = make_float4(0.f, 0.f, 0.f, 0.f);
  if (ADD_BIAS)
    badd = *reinterpret_cast<const float4*>(&bias[n0 + tx * 4]);

#pragma unroll
  for (int i = 0; i < 4; ++i) {
    const int m = m0 + ty * 4 + i;
    float4 r;
    r.x = acc[i][0] + badd.x; r.y = acc[i][1] + badd.y;
    r.z = acc[i][2] + badd.z; r.w = acc[i][3] + badd.w;
    if (SPLIT_HEADS) {
      const int b = m >> 11;          // / Sc
      const int s = m & (Sc - 1);
      const int h = n0 >> 6;          // whole block is one head (64-wide tiles)
      float* dst = Y + ((size_t)(b * Hc + h) * Sc + s) * DKc + tx * 4;
      *reinterpret_cast<float4*>(dst) = r;
    } else {
      *reinterpret_cast<float4*>(Y + (size_t)m * Dc + n0 + tx * 4) = r;
    }
  }
}

// ---------------------------------------------------------------------------
// Flash-style causal attention, fp32. One block = one 64-row Q tile of one
// (b,h). 256 threads, 4x4 micro-tile per thread. Online softmax.
// Q,K,V in [B,H,S,DK]; output written to [B,S,D] (ready for out-projection).
// ---------------------------------------------------------------------------
__global__ __launch_bounds__(256, 3) void attn_kernel(
    const float* __restrict__ Qb, const float* __restrict__ Kb,
    const float* __restrict__ Vb, float* __restrict__ Ab)
{
  const int tx  = threadIdx.x;
  const int ty  = threadIdx.y;
  const int tid = ty * 16 + tx;
  const int q0  = blockIdx.x * 64;
  const int bh  = blockIdx.y;               // b*H + h
  const int b   = bh / Hc;
  const int h   = bh % Hc;

  __shared__ float Qs[64][68];    // [dk][r]   (transposed)
  __shared__ float KPs[64][68];   // K as [dk][c]; later aliased as P [c][r]
  __shared__ float Vs[64][64];    // [c][d]    (natural; reads are row-uniform)

  const float* Qg = Qb + (size_t)bh * Sc * DKc;
  const float* Kg = Kb + (size_t)bh * Sc * DKc;
  const float* Vg = Vb + (size_t)bh * Sc * DKc;

  // ---- load Q tile (transposed into Qs[dk][r]) ----
#pragma unroll
  for (int j = 0; j < 4; ++j) {
    const int f  = tid + j * 256;           // float4 index 0..1023
    const int r  = f >> 4;
    const int dk = (f & 15) * 4;
    const float4 v = *reinterpret_cast<const float4*>(&Qg[(size_t)(q0 + r) * DKc + dk]);
    Qs[dk + 0][r] = v.x; Qs[dk + 1][r] = v.y;
    Qs[dk + 2][r] = v.z; Qs[dk + 3][r] = v.w;
  }

  float o[4][4] = {};
  float m_run[4], l_run[4];
#pragma unroll
  for (int i = 0; i < 4; ++i) { m_run[i] = -1e30f; l_run[i] = 0.f; }

  const int ntiles = blockIdx.x + 1;        // causal: only tiles with k0 <= q0
  for (int kt = 0; kt < ntiles; ++kt) {
    const int k0 = kt * 64;
    __syncthreads();                        // prev PV (reads KPs/Vs) done; Q visible
    // ---- load K (transposed) and V (natural) tiles ----
#pragma unroll
    for (int j = 0; j < 4; ++j) {
      const int f  = tid + j * 256;
      const int r  = f >> 4;
      const int dk = (f & 15) * 4;
      const float4 kv = *reinterpret_cast<const float4*>(&Kg[(size_t)(k0 + r) * DKc + dk]);
      const float4 vv = *reinterpret_cast<const float4*>(&Vg[(size_t)(k0 + r) * DKc + dk]);
      KPs[dk + 0][r] = kv.x; KPs[dk + 1][r] = kv.y;
      KPs[dk + 2][r] = kv.z; KPs[dk + 3][r] = kv.w;
      *reinterpret_cast<float4*>(&Vs[r][dk]) = vv;
    }
    __syncthreads();

    // ---- S = Q K^T ----
    float s[4][4] = {};
#pragma unroll 16
    for (int kk = 0; kk < 64; ++kk) {
      const float4 a  = *reinterpret_cast<const float4*>(&Qs[kk][ty * 4]);
      const float4 c4 = *reinterpret_cast<const float4*>(&KPs[kk][tx * 4]);
      const float aa[4] = {a.x, a.y, a.z, a.w};
      const float cc[4] = {c4.x, c4.y, c4.z, c4.w};
#pragma unroll
      for (int i = 0; i < 4; ++i)
#pragma unroll
        for (int j = 0; j < 4; ++j)
          s[i][j] = fmaf(aa[i], cc[j], s[i][j]);
    }

    // ---- scale + causal mask + online softmax ----
    float p[4][4], mx[4], rs[4];
#pragma unroll
    for (int i = 0; i < 4; ++i) {
      const int qrow = q0 + ty * 4 + i;
#pragma unroll
      for (int j = 0; j < 4; ++j) {
        const int kcol = k0 + tx * 4 + j;
        const float sv = s[i][j] * 0.125f;      // 1/sqrt(64)
        s[i][j] = (kcol > qrow) ? -1e30f : sv;
      }
      mx[i] = fmaxf(fmaxf(s[i][0], s[i][1]), fmaxf(s[i][2], s[i][3]));
    }
#pragma unroll
    for (int off = 1; off < 16; off <<= 1)
#pragma unroll
      for (int i = 0; i < 4; ++i)
        mx[i] = fmaxf(mx[i], __shfl_xor(mx[i], off));

#pragma unroll
    for (int i = 0; i < 4; ++i) {
      const float mnew  = fmaxf(m_run[i], mx[i]);
      const float alpha = __expf(m_run[i] - mnew);
      m_run[i] = mnew;
      float r0 = 0.f;
#pragma unroll
      for (int j = 0; j < 4; ++j) {
        p[i][j] = __expf(s[i][j] - mnew);
        r0 += p[i][j];
      }
      rs[i] = r0;
#pragma unroll
      for (int j = 0; j < 4; ++j) o[i][j] *= alpha;
      l_run[i] *= alpha;
    }
#pragma unroll
    for (int off = 1; off < 16; off <<= 1)
#pragma unroll
      for (int i = 0; i < 4; ++i)
        rs[i] += __shfl_xor(rs[i], off);
#pragma unroll
    for (int i = 0; i < 4; ++i) l_run[i] += rs[i];

    __syncthreads();                        // everyone done reading K from KPs
    // ---- write P transposed: P[c][r] (aliases K buffer) ----
#pragma unroll
    for (int i = 0; i < 4; ++i)
#pragma unroll
      for (int j = 0; j < 4; ++j)
        KPs[tx * 4 + j][ty * 4 + i] = p[i][j];
    __syncthreads();

    // ---- O += P V ----
#pragma unroll 16
    for (int c = 0; c < 64; ++c) {
      const float4 pv = *reinterpret_cast<const float4*>(&KPs[c][ty * 4]);
      const float4 vv = *reinterpret_cast<const float4*>(&Vs[c][tx * 4]);
      const float pp[4] = {pv.x, pv.y, pv.z, pv.w};
      const float vw[4] = {vv.x, vv.y, vv.z, vv.w};
#pragma unroll
      for (int i = 0; i < 4; ++i)
#pragma unroll
        for (int j = 0; j < 4; ++j)
          o[i][j] = fmaf(pp[i], vw[j], o[i][j]);
    }
  }

  // ---- epilogue: normalize and write [B,S,D] ----
#pragma unroll
  for (int i = 0; i < 4; ++i) {
    const float rl = 1.f / l_run[i];
    const int   q  = q0 + ty * 4 + i;
    float4 r;
    r.x = o[i][0] * rl; r.y = o[i][1] * rl;
    r.z = o[i][2] * rl; r.w = o[i][3] * rl;
    *reinterpret_cast<float4*>(&Ab[((size_t)b * Sc + q) * Dc + h * DKc + tx * 4]) = r;
  }
}

}  // namespace

extern "C" void kernel_launch(void* const* d_in, const int* in_sizes, int n_in,
                              void* d_out, int out_size, void* d_ws, size_t ws_size,
                              hipStream_t stream) {
  const float* q  = (const float*)d_in[0];
  const float* k  = (const float*)d_in[1];
  const float* v  = (const float*)d_in[2];
  // d_in[3] = causal mask (bool [B,S,S]) — structure known, not read
  const float* wq = (const float*)d_in[4];
  const float* wk = (const float*)d_in[5];
  const float* wv = (const float*)d_in[6];
  const float* wo = (const float*)d_in[7];
  const float* bo = (const float*)d_in[8];
  float* out = (float*)d_out;
  float* ws  = (float*)d_ws;

  const size_t NQ = (size_t)Bc * Sc * Dc;   // 3,145,728 floats per buffer
  float* Qbuf = ws;
  float* Kbuf = ws + NQ;
  float* Vbuf = ws + 2 * NQ;
  float* Abuf = ws + 3 * NQ;                // total 50.3 MB of d_ws

  const dim3 blk(16, 16);
  const dim3 gproj(Mc / 64, Dc / 64);       // 64 x 12
  const dim3 gattn(Sc / 64, Bc * Hc);       // 32 x 24

  proj_kernel<true,  false><<<gproj, blk, 0, stream>>>(q, wq, nullptr, Qbuf);
  proj_kernel<true,  false><<<gproj, blk, 0, stream>>>(k, wk, nullptr, Kbuf);
  proj_kernel<true,  false><<<gproj, blk, 0, stream>>>(v, wv, nullptr, Vbuf);
  attn_kernel<<<gattn, blk, 0, stream>>>(Qbuf, Kbuf, Vbuf, Abuf);
  proj_kernel<false, true ><<<gproj, blk, 0, stream>>>(Abuf, wo, bo, out);
}

// Round 2
// 335.980 us; speedup vs baseline: 2.3027x; 2.3027x over previous
//
#include <hip/hip_runtime.h>

namespace {
constexpr int Sc = 2048, Dc = 768, Hc = 12, Mc = 4096;

using fragb = __attribute__((ext_vector_type(8))) short;   // 8 bf16 (4 VGPRs)
using f32x4 = __attribute__((ext_vector_type(4))) float;   // MFMA C/D

#define MFMA16(A, B, C) __builtin_amdgcn_mfma_f32_16x16x32_bf16(A, B, C, 0, 0, 0)

// fp32 -> bf16 bits, round-to-nearest-even (finite inputs)
__device__ __forceinline__ unsigned short bf16hi(float f) {
  unsigned int u = __float_as_uint(f);
  return (unsigned short)((u + 0x7fffu + ((u >> 16) & 1u)) >> 16);
}
__device__ __forceinline__ float fbf(unsigned short h) {
  return __uint_as_float((unsigned int)h << 16);
}
// pack x as (hi bf16 | lo bf16), x ~= hi + lo to ~16 mantissa bits
__device__ __forceinline__ unsigned int packsplit(float f) {
  unsigned short h = bf16hi(f);
  unsigned short l = bf16hi(f - fbf(h));
  return ((unsigned int)h << 16) | (unsigned int)l;
}
__device__ __forceinline__ void split8(const float* x, fragb& hv, fragb& lv) {
  union { fragb v; short s[8]; } h, l;
#pragma unroll
  for (int i = 0; i < 8; ++i) {
    unsigned short hh = bf16hi(x[i]);
    h.s[i] = (short)hh;
    l.s[i] = (short)bf16hi(x[i] - fbf(hh));
  }
  hv = h.v; lv = l.v;
}
__device__ __forceinline__ void unpack8(const unsigned int* u, fragb& hv, fragb& lv) {
  union { fragb v; short s[8]; } h, l;
#pragma unroll
  for (int i = 0; i < 8; ++i) {
    h.s[i] = (short)(u[i] >> 16);
    l.s[i] = (short)(u[i] & 0xffffu);
  }
  hv = h.v; lv = l.v;
}

// ---------------------------------------------------------------------------
// Y = X @ W^T (+bias), split-bf16 MFMA (hh + hl + lh), fp32 accumulate.
// 64x64 tile, BK=32, 256 threads (4 waves; wave w owns rows 16w..16w+15).
// AMODE: 0 = fp32 source, 1 = packed (hi|lo) u32 source.
// OMODE: 0 = packed u32 [b,h,s,dk]; 1 = packed u32 [b,h,dk,s] (V transposed);
//        2 = fp32 [M][D] + bias.
// ---------------------------------------------------------------------------
template <int AMODE, int OMODE>
__global__ __launch_bounds__(256, 3) void proj_kernel(
    const void* __restrict__ Asrc, const float* __restrict__ W,
    const float* __restrict__ bias, void* __restrict__ Out)
{
  const int tid = threadIdx.x;
  const int lane = tid & 63, w = tid >> 6;
  const int g = lane >> 4, l15 = lane & 15;
  const int m0 = blockIdx.x * 64, n0 = blockIdx.y * 64;

  // stride 40 bf16 = 80 B: 16B-aligned rows, banks spread ~8/bank for b128
  __shared__ __align__(16) short Ah[64][40], Al[64][40];
  __shared__ __align__(16) short Bh[64][40], Bl[64][40];

  f32x4 acc[4] = {};

  const int srow = tid >> 2;          // staging row 0..63
  const int scol = (tid & 3) * 8;     // staging k-offset 0/8/16/24

  for (int k0 = 0; k0 < Dc; k0 += 32) {
    // ---- global loads + convert (before barrier; overlaps other waves) ----
    fragb ah_s, al_s, bh_s, bl_s;
    if (AMODE == 0) {
      const float* ap = (const float*)Asrc + (size_t)(m0 + srow) * Dc + k0 + scol;
      float4 v0 = *(const float4*)(ap);
      float4 v1 = *(const float4*)(ap + 4);
      float xa[8] = {v0.x, v0.y, v0.z, v0.w, v1.x, v1.y, v1.z, v1.w};
      split8(xa, ah_s, al_s);
    } else {
      const unsigned int* ap = (const unsigned int*)Asrc + (size_t)(m0 + srow) * Dc + k0 + scol;
      uint4 v0 = *(const uint4*)(ap);
      uint4 v1 = *(const uint4*)(ap + 4);
      unsigned int ua[8] = {v0.x, v0.y, v0.z, v0.w, v1.x, v1.y, v1.z, v1.w};
      unpack8(ua, ah_s, al_s);
    }
    {
      const float* wp = W + (size_t)(n0 + srow) * Dc + k0 + scol;
      float4 v0 = *(const float4*)(wp);
      float4 v1 = *(const float4*)(wp + 4);
      float xw[8] = {v0.x, v0.y, v0.z, v0.w, v1.x, v1.y, v1.z, v1.w};
      split8(xw, bh_s, bl_s);
    }
    __syncthreads();                  // previous tile's compute done
    *(fragb*)&Ah[srow][scol] = ah_s;
    *(fragb*)&Al[srow][scol] = al_s;
    *(fragb*)&Bh[srow][scol] = bh_s;
    *(fragb*)&Bl[srow][scol] = bl_s;
    __syncthreads();

    // ---- compute: A-frag row = l15 (within wave's 16-row strip), k = 8g+j ----
    const fragb aH = *(const fragb*)&Ah[16 * w + l15][8 * g];
    const fragb aL = *(const fragb*)&Al[16 * w + l15][8 * g];
#pragma unroll
    for (int nb = 0; nb < 4; ++nb) {
      const fragb bH = *(const fragb*)&Bh[nb * 16 + l15][8 * g];
      const fragb bL = *(const fragb*)&Bl[nb * 16 + l15][8 * g];
      acc[nb] = MFMA16(aH, bH, acc[nb]);
      acc[nb] = MFMA16(aH, bL, acc[nb]);
      acc[nb] = MFMA16(aL, bH, acc[nb]);
    }
  }

  // ---- epilogue: C/D layout col = l15, row = 4g + r ----
  const int mrow = m0 + 16 * w + 4 * g;
  if (OMODE == 2) {
#pragma unroll
    for (int nb = 0; nb < 4; ++nb) {
      const int n = n0 + nb * 16 + l15;
      const float bv = bias[n];
#pragma unroll
      for (int r = 0; r < 4; ++r)
        ((float*)Out)[(size_t)(mrow + r) * Dc + n] = acc[nb][r] + bv;
    }
  } else {
#pragma unroll
    for (int nb = 0; nb < 4; ++nb) {
      const int n = n0 + nb * 16 + l15;
      const int hh = n >> 6, dk = n & 63;
#pragma unroll
      for (int r = 0; r < 4; ++r) {
        const int m = mrow + r;
        const int bb = m >> 11, s = m & (Sc - 1);
        const size_t idx = (OMODE == 0)
            ? (((size_t)bb * Hc + hh) * Sc + s) * 64 + dk
            : (((size_t)bb * Hc + hh) * 64 + dk) * Sc + s;
        ((unsigned int*)Out)[idx] = packsplit(acc[nb][r]);
      }
    }
  }
}

// ---------------------------------------------------------------------------
// Flash-style causal attention on split-bf16 MFMA.
// Block = complementary 32-row Q-tile pair (t, 63-t) => uniform work/block.
// 256 threads / 4 waves; waves 0,1 -> tile t, waves 2,3 -> tile 63-t;
// each wave owns 16 Q rows. K-tiles of 64 keys, shared staging.
// QK^T: 3-term split (qh*kh + qh*kl + ql*kh); PV: P(bf16) * (Vh + Vl).
// ---------------------------------------------------------------------------
__global__ __launch_bounds__(256, 3) void attn_kernel(
    const unsigned int* __restrict__ Qp, const unsigned int* __restrict__ Kp,
    const unsigned int* __restrict__ Vtg, unsigned int* __restrict__ att2)
{
  const int tid = threadIdx.x;
  const int lane = tid & 63, w = tid >> 6;
  const int g = lane >> 4, l15 = lane & 15;
  const int t = blockIdx.x;                 // pair id 0..31
  const int bh = blockIdx.y;
  const int b = bh / Hc, h = bh % Hc;

  const int qtile = (w < 2) ? t : (63 - t);
  const int qbase = qtile * 32 + (w & 1) * 16;
  const int ktmax = (qbase + 15) >> 6;                 // last k-tile this wave needs
  const int NKT = ((Sc - 1 - 32 * t) >> 6) + 1;        // block loop count (B-tile governs)

  // stride 72 bf16 = 144 B: 16B-aligned rows, near-uniform bank spread
  __shared__ __align__(16) short Ks_h[64][72], Ks_l[64][72];
  __shared__ __align__(16) short Vt_h[64][72], Vt_l[64][72];
  __shared__ __align__(16) short Ps[64][72];

  // ---- Q fragments in registers (A-frag: row=l15, k=32c+8g+j) ----
  fragb qh[2], ql[2];
  {
    const unsigned int* qrow = Qp + ((size_t)bh * Sc + qbase + l15) * 64;
#pragma unroll
    for (int c = 0; c < 2; ++c) {
      uint4 v0 = *(const uint4*)(qrow + c * 32 + g * 8);
      uint4 v1 = *(const uint4*)(qrow + c * 32 + g * 8 + 4);
      unsigned int u[8] = {v0.x, v0.y, v0.z, v0.w, v1.x, v1.y, v1.z, v1.w};
      unpack8(u, qh[c], ql[c]);
    }
  }

  f32x4 oacc[4] = {};
  float m_run[4] = {-1e30f, -1e30f, -1e30f, -1e30f};
  float l_run[4] = {0.f, 0.f, 0.f, 0.f};

  const int srow = tid >> 2;          // K: key row / V: dk row
  const int scol = (tid & 3) * 16;    // K: dk offset / V: key offset

  for (int kt = 0; kt < NKT; ++kt) {
    const int k0 = kt * 64;
    // ---- issue global loads before barrier ----
    uint4 ka[4], va[4];
    {
      const unsigned int* kp = Kp + ((size_t)bh * Sc + k0 + srow) * 64 + scol;
      const unsigned int* vp = Vtg + ((size_t)bh * 64 + srow) * Sc + k0 + scol;
#pragma unroll
      for (int u = 0; u < 4; ++u) {
        ka[u] = *(const uint4*)(kp + 4 * u);
        va[u] = *(const uint4*)(vp + 4 * u);
      }
    }
    __syncthreads();                  // all waves done with prev tile's LDS
    {
      fragb h0, l0, h1, l1;
      unsigned int u[8];
      u[0]=ka[0].x; u[1]=ka[0].y; u[2]=ka[0].z; u[3]=ka[0].w;
      u[4]=ka[1].x; u[5]=ka[1].y; u[6]=ka[1].z; u[7]=ka[1].w;
      unpack8(u, h0, l0);
      u[0]=ka[2].x; u[1]=ka[2].y; u[2]=ka[2].z; u[3]=ka[2].w;
      u[4]=ka[3].x; u[5]=ka[3].y; u[6]=ka[3].z; u[7]=ka[3].w;
      unpack8(u, h1, l1);
      *(fragb*)&Ks_h[srow][scol]     = h0;
      *(fragb*)&Ks_h[srow][scol + 8] = h1;
      *(fragb*)&Ks_l[srow][scol]     = l0;
      *(fragb*)&Ks_l[srow][scol + 8] = l1;
      u[0]=va[0].x; u[1]=va[0].y; u[2]=va[0].z; u[3]=va[0].w;
      u[4]=va[1].x; u[5]=va[1].y; u[6]=va[1].z; u[7]=va[1].w;
      unpack8(u, h0, l0);
      u[0]=va[2].x; u[1]=va[2].y; u[2]=va[2].z; u[3]=va[2].w;
      u[4]=va[3].x; u[5]=va[3].y; u[6]=va[3].z; u[7]=va[3].w;
      unpack8(u, h1, l1);
      *(fragb*)&Vt_h[srow][scol]     = h0;
      *(fragb*)&Vt_h[srow][scol + 8] = h1;
      *(fragb*)&Vt_l[srow][scol]     = l0;
      *(fragb*)&Vt_l[srow][scol + 8] = l1;
    }
    __syncthreads();

    if (kt <= ktmax) {                // wave-uniform branch
      // ---- S = Q K^T (B-frag of K^T == A-pattern read of K rows) ----
      f32x4 sacc[4] = {};
#pragma unroll
      for (int c = 0; c < 2; ++c) {
#pragma unroll
        for (int kb = 0; kb < 4; ++kb) {
          const fragb kH = *(const fragb*)&Ks_h[kb * 16 + l15][c * 32 + g * 8];
          const fragb kL = *(const fragb*)&Ks_l[kb * 16 + l15][c * 32 + g * 8];
          sacc[kb] = MFMA16(qh[c], kH, sacc[kb]);
          sacc[kb] = MFMA16(qh[c], kL, sacc[kb]);
          sacc[kb] = MFMA16(ql[c], kH, sacc[kb]);
        }
      }
      // ---- scale + causal mask + online softmax (rows live in 16-lane groups) ----
      float p[4][4], mx[4];
#pragma unroll
      for (int r = 0; r < 4; ++r) {
        const int qrow = qbase + 4 * g + r;
#pragma unroll
        for (int kb = 0; kb < 4; ++kb) {
          const int kc = k0 + kb * 16 + l15;
          const float x = sacc[kb][r] * 0.125f;    // 1/sqrt(64)
          p[kb][r] = (kc > qrow) ? -1e30f : x;
        }
        mx[r] = fmaxf(fmaxf(p[0][r], p[1][r]), fmaxf(p[2][r], p[3][r]));
      }
#pragma unroll
      for (int off = 8; off > 0; off >>= 1)
#pragma unroll
        for (int r = 0; r < 4; ++r)
          mx[r] = fmaxf(mx[r], __shfl_xor(mx[r], off));
#pragma unroll
      for (int r = 0; r < 4; ++r) {
        const float mnew = fmaxf(m_run[r], mx[r]);
        const float alpha = __expf(m_run[r] - mnew);
        m_run[r] = mnew;
        float rs = 0.f;
#pragma unroll
        for (int kb = 0; kb < 4; ++kb) { p[kb][r] = __expf(p[kb][r] - mnew); rs += p[kb][r]; }
#pragma unroll
        for (int off = 8; off > 0; off >>= 1) rs += __shfl_xor(rs, off);
        l_run[r] = l_run[r] * alpha + rs;
#pragma unroll
        for (int db = 0; db < 4; ++db) oacc[db][r] *= alpha;
      }
      // ---- P -> LDS (own wave strip; within-wave write->read ordering) ----
      const int strip = 16 * w;
#pragma unroll
      for (int kb = 0; kb < 4; ++kb)
#pragma unroll
        for (int r = 0; r < 4; ++r)
          Ps[strip + 4 * g + r][kb * 16 + l15] = (short)bf16hi(p[kb][r]);
      // ---- O += P (Vh + Vl) ----
#pragma unroll
      for (int c = 0; c < 2; ++c) {
        const fragb pf = *(const fragb*)&Ps[strip + l15][c * 32 + g * 8];
#pragma unroll
        for (int db = 0; db < 4; ++db) {
          const fragb vH = *(const fragb*)&Vt_h[db * 16 + l15][c * 32 + g * 8];
          const fragb vL = *(const fragb*)&Vt_l[db * 16 + l15][c * 32 + g * 8];
          oacc[db] = MFMA16(pf, vH, oacc[db]);
          oacc[db] = MFMA16(pf, vL, oacc[db]);
        }
      }
    }
  }

  // ---- epilogue: normalize, write packed attended [B,S,D] ----
#pragma unroll
  for (int r = 0; r < 4; ++r) {
    const float rl = 1.0f / l_run[r];
    const int s = qbase + 4 * g + r;
    unsigned int* orow = att2 + ((size_t)b * Sc + s) * Dc + h * 64 + l15;
#pragma unroll
    for (int db = 0; db < 4; ++db)
      orow[db * 16] = packsplit(oacc[db][r] * rl);
  }
}

}  // namespace

extern "C" void kernel_launch(void* const* d_in, const int* in_sizes, int n_in,
                              void* d_out, int out_size, void* d_ws, size_t ws_size,
                              hipStream_t stream) {
  const float* q  = (const float*)d_in[0];
  const float* k  = (const float*)d_in[1];
  const float* v  = (const float*)d_in[2];
  // d_in[3] = causal mask (bool) — structure known, not read
  const float* wq = (const float*)d_in[4];
  const float* wk = (const float*)d_in[5];
  const float* wv = (const float*)d_in[6];
  const float* wo = (const float*)d_in[7];
  const float* bo = (const float*)d_in[8];

  unsigned int* ws   = (unsigned int*)d_ws;
  const size_t NQ = (size_t)Mc * Dc;        // 3,145,728 packed u32 per buffer
  unsigned int* Qp   = ws;                  // [b,h,s,dk] packed hi|lo
  unsigned int* Kp   = ws + NQ;
  unsigned int* Vtg  = ws + 2 * NQ;         // [b,h,dk,s] packed hi|lo
  unsigned int* att2 = ws + 3 * NQ;         // [b,s,d]    packed hi|lo   (50.3 MB total)

  const dim3 blk(256);
  const dim3 gproj(Mc / 64, Dc / 64);       // 64 x 12 = 768 blocks
  const dim3 gattn(32, 2 * Hc);             // 32 pairs x 24 (b,h)

  proj_kernel<0, 0><<<gproj, blk, 0, stream>>>(q, wq, nullptr, Qp);
  proj_kernel<0, 0><<<gproj, blk, 0, stream>>>(k, wk, nullptr, Kp);
  proj_kernel<0, 1><<<gproj, blk, 0, stream>>>(v, wv, nullptr, Vtg);
  attn_kernel<<<gattn, blk, 0, stream>>>(Qp, Kp, Vtg, att2);
  proj_kernel<1, 2><<<gproj, blk, 0, stream>>>(att2, wo, bo, d_out);
}